// Round 17
// baseline (505.449 us; speedup 1.0000x reference)
//
#include <hip/hip_runtime.h>
#include <hip/hip_bf16.h>
#include <hip/hip_fp16.h>

// Problem constants
#define TT 16
#define NN 2048          // B*S
#define DD 1024
#define MM 1024
#define HH 8
#define ROWS 32768       // T*N
#define JJ 2048          // 2*M (mi | gi packed)

typedef _Float16 f16x8 __attribute__((ext_vector_type(8)));
typedef float f32x4 __attribute__((ext_vector_type(4)));
typedef unsigned short u16x8 __attribute__((ext_vector_type(8)));

#define SB  __builtin_amdgcn_sched_barrier(0)
#define BAR __builtin_amdgcn_s_barrier()

__device__ __forceinline__ void gload16(const void* g, void* l) {
    __builtin_amdgcn_global_load_lds((const __attribute__((address_space(1))) void*)g,
                                     (__attribute__((address_space(3))) void*)l, 16, 0, 0);
}

// ---------------- pack fp32 -> f16 hi only (row-major, for W_from) ----------------
__global__ __launch_bounds__(256) void pack_hi(const float* __restrict__ in,
                                               __half* __restrict__ hi, long n4) {
    long i = (long)blockIdx.x * 256 + threadIdx.x;
    if (i >= n4) return;
    float4 v = ((const float4*)in)[i];
    ushort4 H = { __half_as_ushort(__float2half(v.x)), __half_as_ushort(__float2half(v.y)),
                  __half_as_ushort(__float2half(v.z)), __half_as_ushort(__float2half(v.w)) };
    ((ushort4*)hi)[i] = H;
}

// ---------------- pack fp32 -> f16 hi/lo into TILED K-major global layout ----
// Output: per 256-row block rblk, per BK=32 k-tile kt: 16KB tile
//   [slot 0..3][row 0..255][16B(8 halfs)], tiles ordered (rblk*32 + kt).
// Tile (rblk,kt) slot s row r holds halfs of floats in[src_row][kt*32+s*8 .. +8]
// (slot = k-slot l4 of the 16x16x32 fragment).
// PERM=true applies the 16x16 LIF row permutation (R8):
//   r bits [n3 n2 t3 t2 n1 n0 t1 t0]:
//   t = ((r>>4)&3)*4 + (r&3), n_l = ((r>>7)&1)*8+((r>>6)&1)*4+((r>>2)&3)
// One block = (rblk, kt2), kt2 covers kt = 2*kt2, 2*kt2+1 (64 floats of k).
template<bool PERM>
__global__ __launch_bounds__(256)
void pack_tiled(const float* __restrict__ in, __half* __restrict__ hi,
                __half* __restrict__ lo) {
    const int rblk = blockIdx.x >> 4;
    const int kt2  = blockIdx.x & 15;
    const int r    = threadIdx.x;
    int src_row;
    if (PERM) {
        int t   = ((r >> 4) & 3) * 4 + (r & 3);
        int n_l = ((r >> 7) & 1) * 8 + ((r >> 6) & 1) * 4 + ((r >> 2) & 3);
        src_row = t * NN + rblk * 16 + n_l;
    } else {
        src_row = rblk * 256 + r;
    }
    const float4* s4 = (const float4*)(in + (size_t)src_row * 1024 + kt2 * 64);
    float f[64];
    #pragma unroll
    for (int q = 0; q < 16; q++) {
        float4 v = s4[q];
        f[q * 4 + 0] = v.x; f[q * 4 + 1] = v.y; f[q * 4 + 2] = v.z; f[q * 4 + 3] = v.w;
    }
    #pragma unroll
    for (int j = 0; j < 8; j++) {           // j -> (kt_local = j>>2, slot = j&3)
        u16x8 H, L;
        #pragma unroll
        for (int e = 0; e < 8; e++) {
            float x = f[j * 8 + e];
            __half h = __float2half(x);
            H[e] = __half_as_ushort(h);
            L[e] = __half_as_ushort(__float2half(x - __half2float(h)));
        }
        size_t off = ((size_t)(rblk * 32 + kt2 * 2 + (j >> 2))) * 8192 + (j & 3) * 2048 + r * 8;
        *(u16x8*)(hi + off) = H;
        *(u16x8*)(lo + off) = L;
    }
}

// ---- merged W pack: blocks [0,64) pack Wto, [64,128) pack Wg (both tiled) ----
__global__ __launch_bounds__(256)
void pack_tiled_w(const float* __restrict__ Wto, const float* __restrict__ Wg,
                  __half* __restrict__ hi, __half* __restrict__ lo) {
    const int half = blockIdx.x >> 6;         // 0: Wto, 1: Wg
    const int bid  = blockIdx.x & 63;
    const int rblk = bid >> 4;
    const int kt2  = bid & 15;
    const int r    = threadIdx.x;
    const float* in = half ? Wg : Wto;
    __half* hio = hi + (size_t)half * MM * DD;
    __half* loo = lo + (size_t)half * MM * DD;
    const int src_row = rblk * 256 + r;
    const float4* s4 = (const float4*)(in + (size_t)src_row * 1024 + kt2 * 64);
    float f[64];
    #pragma unroll
    for (int q = 0; q < 16; q++) {
        float4 v = s4[q];
        f[q * 4 + 0] = v.x; f[q * 4 + 1] = v.y; f[q * 4 + 2] = v.z; f[q * 4 + 3] = v.w;
    }
    #pragma unroll
    for (int j = 0; j < 8; j++) {
        u16x8 H, L;
        #pragma unroll
        for (int e = 0; e < 8; e++) {
            float x = f[j * 8 + e];
            __half h = __float2half(x);
            H[e] = __half_as_ushort(h);
            L[e] = __half_as_ushort(__float2half(x - __half2float(h)));
        }
        size_t off = ((size_t)(rblk * 32 + kt2 * 2 + (j >> 2))) * 8192 + (j & 3) * 2048 + r * 8;
        *(u16x8*)(hio + off) = H;
        *(u16x8*)(loo + off) = L;
    }
}

// ---------------- wq[h][m] = scale * sum_hd q[h,hd]*Wrk[h*128+hd, m] ----------------
__global__ __launch_bounds__(256) void compute_wq(const float* __restrict__ Wrk,
                                                  const float* __restrict__ q,
                                                  float* __restrict__ wq) {
    int m = blockIdx.x * 256 + threadIdx.x;   // 0..1023
    int h = blockIdx.y;                        // 0..7
    const float* qh = q + h * 128;
    const float* wr = Wrk + (size_t)h * 128 * MM + m;
    float acc = 0.f;
    for (int hd = 0; hd < 128; hd++) acc = fmaf(qh[hd], wr[(size_t)hd * MM], acc);
    wq[h * MM + m] = acc * 0.08838834764831845f;   // 1/sqrt(128)
}

// =============================================================================
// 256x256 3-term f16 GEMM, 16x16x32 MFMA (triplet {Ahi*Bh, Ahi*Bl, Alo*Bh},
// barrier-slim) + FUSED LIF EPILOGUE. Tiled K-major global layout.
// R15 structure (best measured: 296.7 us, MfmaUtil 65%): phased triplet,
// one vmcnt(0)+s_barrier per triplet; staging = pure linear 16KB copy;
// fragment read = slot(l4)*4096 + row*16 (conflict-free, no swizzle VALU).
// R16's flattened variant regressed (compiler already pipelines the phases).
// =============================================================================
__global__ __launch_bounds__(512, 2)
void gemm8p(const __half* __restrict__ Ahi, const __half* __restrict__ Alo,
            const __half* __restrict__ Bhi, const __half* __restrict__ Blo,
            __half* __restrict__ mv, float* __restrict__ gmask,
            const float* __restrict__ gate_thr)
{
    extern __shared__ __align__(16) char smem[];
    char* AHb = smem;                 // [2 parity][16384 B] each
    char* ALb = smem + 32768;
    char* BHb = smem + 65536;
    char* BLb = smem + 98304;

    const int tid = threadIdx.x, lane = tid & 63, wave = tid >> 6;
    const int l15 = lane & 15, l4 = lane >> 4;
    const int wm = wave >> 2, wn = wave & 3;

    // XCD-contiguous swizzle (1024 blocks), col-fastest within chunk.
    const int orig = blockIdx.x;
    const int wg   = (orig & 7) * 128 + (orig >> 3);
    const int rb   = (wg >> 3) * 256;
    const int cb   = (wg & 7) * 256;

    // Stage 8KB slice s of a 16KB K-major tile: pure linear copy.
    auto stageU = [&](const __half* src, int row0, char* dstbase, int par, int kt, int s) {
        const char* g = (const char*)(src + (size_t)((row0 >> 8) * 32 + kt) * 8192)
                        + (size_t)(s * 512 + tid) * 16;
        gload16(g, dstbase + par * 16384 + (size_t)(s * 512 + wave * 64) * 16);
    };
    // 16x16 fragment read: lane -> slot l4, row = caller's rowblk + l15.
    auto rdT = [&](const char* base, int par, int row) -> f16x8 {
        return *(const f16x8*)(base + par * 16384 + l4 * 4096 + row * 16);
    };

    f32x4 acc[8][4] = {};
    const int NKT = 32;                     // k0 triplets

    // Prologue: stage triplet 0 (parity 0), 8 loads/thread.
    stageU(Ahi, rb, AHb, 0, 0, 0); stageU(Ahi, rb, AHb, 0, 0, 1);
    stageU(Alo, rb, ALb, 0, 0, 0); stageU(Alo, rb, ALb, 0, 0, 1);
    stageU(Bhi, cb, BHb, 0, 0, 0); stageU(Bhi, cb, BHb, 0, 0, 1);
    stageU(Blo, cb, BLb, 0, 0, 0); stageU(Blo, cb, BLb, 0, 0, 1);

    for (int kt = 0; kt < NKT; kt++) {
        const int p = kt & 1, pn = p ^ 1;
        const bool pre = (kt + 1 < NKT);
        f16x8 a[8], bh[4], bl[4];

        // ---- triplet-start sync: parity-p tiles all present across waves
        asm volatile("s_waitcnt vmcnt(0)" ::: "memory");
        SB; BAR;

        #pragma unroll
        for (int i = 0; i < 8; i++) a[i] = rdT(AHb, p, wm * 128 + i * 16 + l15);
        #pragma unroll
        for (int n = 0; n < 4; n++) bh[n] = rdT(BHb, p, wn * 64 + n * 16 + l15);
        if (pre) {
            stageU(Ahi, rb, AHb, pn, kt + 1, 0); stageU(Ahi, rb, AHb, pn, kt + 1, 1);
            stageU(Alo, rb, ALb, pn, kt + 1, 0); stageU(Alo, rb, ALb, pn, kt + 1, 1);
        }
        __builtin_amdgcn_s_setprio(1);
        #pragma unroll
        for (int i = 0; i < 8; i++)
            #pragma unroll
            for (int n = 0; n < 4; n++)
                acc[i][n] = __builtin_amdgcn_mfma_f32_16x16x32_f16(a[i], bh[n], acc[i][n], 0, 0, 0);
        __builtin_amdgcn_s_setprio(0);

        #pragma unroll
        for (int n = 0; n < 4; n++) bl[n] = rdT(BLb, p, wn * 64 + n * 16 + l15);
        if (pre) {
            stageU(Bhi, cb, BHb, pn, kt + 1, 0); stageU(Bhi, cb, BHb, pn, kt + 1, 1);
        }
        __builtin_amdgcn_s_setprio(1);
        #pragma unroll
        for (int i = 0; i < 8; i++)
            #pragma unroll
            for (int n = 0; n < 4; n++)
                acc[i][n] = __builtin_amdgcn_mfma_f32_16x16x32_f16(a[i], bl[n], acc[i][n], 0, 0, 0);
        __builtin_amdgcn_s_setprio(0);

        #pragma unroll
        for (int i = 0; i < 8; i++) a[i] = rdT(ALb, p, wm * 128 + i * 16 + l15);
        if (pre) {
            stageU(Blo, cb, BLb, pn, kt + 1, 0); stageU(Blo, cb, BLb, pn, kt + 1, 1);
        }
        __builtin_amdgcn_s_setprio(1);
        #pragma unroll
        for (int i = 0; i < 8; i++)
            #pragma unroll
            for (int n = 0; n < 4; n++)
                acc[i][n] = __builtin_amdgcn_mfma_f32_16x16x32_f16(a[i], bh[n], acc[i][n], 0, 0, 0);
        __builtin_amdgcn_s_setprio(0);
    }

    // ===== fused LIF epilogue =====
    asm volatile("s_waitcnt lgkmcnt(0) vmcnt(0)" ::: "memory");
    SB; BAR;

    const int n_g_base = rb >> 4;       // 16 n per block
    if (cb < 1024) {
        // memory path: tau=0.99, pre-reset trace -> LDS [16t][16n][256m] f16 -> mv
        __half* mvs = (__half*)smem;
        #pragma unroll
        for (int i2 = 0; i2 < 2; i2++) {
            int n_l = wm * 8 + i2 * 4 + l4;
            #pragma unroll
            for (int nf = 0; nf < 4; nf++) {
                int col = wn * 64 + nf * 16 + l15;
                float v = 0.f;
                #pragma unroll
                for (int tt = 0; tt < 4; tt++)
                    #pragma unroll
                    for (int reg = 0; reg < 4; reg++) {
                        int t = tt * 4 + reg;
                        v = 0.99f * v + acc[i2 * 4 + tt][nf][reg];
                        mvs[(t * 16 + n_l) * 256 + col] = __float2half(v);
                        if (v >= 1.0f) v -= 1.0f;
                    }
            }
        }
        SB; BAR;
        // cooperative vector store: 8192 x 16B chunks
        #pragma unroll
        for (int j = 0; j < 16; j++) {
            int k = j * 512 + tid;
            int e = k * 8;
            int t   = e >> 12;
            int n_l = (e >> 8) & 15;
            int m   = e & 255;
            float4 val = *(const float4*)((const char*)smem + (size_t)k * 16);
            *(float4*)(mv + ((size_t)(t * NN + n_g_base + n_l) * MM + cb + m)) = val;
        }
    } else {
        // gate path: tau=0.9, spike count -> gmask
        float thr = gate_thr[0];
        #pragma unroll
        for (int i2 = 0; i2 < 2; i2++) {
            int n_l = wm * 8 + i2 * 4 + l4;
            #pragma unroll
            for (int nf = 0; nf < 4; nf++) {
                int col = wn * 64 + nf * 16 + l15;
                float v = 0.f, cnt = 0.f;
                #pragma unroll
                for (int tt = 0; tt < 4; tt++)
                    #pragma unroll
                    for (int reg = 0; reg < 4; reg++) {
                        v = 0.9f * v + acc[i2 * 4 + tt][nf][reg];
                        if (v >= 1.0f) { v -= 1.0f; cnt += 1.0f; }
                    }
                float gs = cnt * 0.0625f;
                gmask[(size_t)(n_g_base + n_l) * MM + (cb - 1024) + col] =
                    1.0f / (1.0f + expf(-10.0f * (gs - thr)));
            }
        }
    }
}

// ---------------- 128x128 f16 GEMM (kept for the small projection) ----------------
template<int TERMS>
__global__ __launch_bounds__(256, 2)
void gemm_f16(const __half* __restrict__ Ahi, const __half* __restrict__ Alo,
              const __half* __restrict__ Bhi, const __half* __restrict__ Blo,
              float* __restrict__ C, int K, int ldc, int ncb_log2)
{
    __shared__ __align__(16) __half lds[2][4][8][512];
    const int tid  = threadIdx.x;
    const int lane = tid & 63;
    const int wave = tid >> 6;
    const int l15  = lane & 15, l4 = lane >> 4;

    const int nwg  = gridDim.x;
    const int orig = blockIdx.x;
    const int wg   = (orig & 7) * (nwg >> 3) + (orig >> 3);
    const int rb = (wg >> ncb_log2) * 128;
    const int cb = (wg & ((1 << ncb_log2) - 1)) * 128;

    auto stage = [&](int buf, int ks) {
        const int k0 = ks * 32;
        #pragma unroll
        for (int qq = 0; qq < 2; qq++) {
            int g = wave * 2 + qq;
            size_t aoff = (size_t)(rb + g * 16 + l15) * K + (k0 + 8 * l4);
            gload16(Ahi + aoff, &lds[buf][0][g][0]);
            if constexpr (TERMS == 3) gload16(Alo + aoff, &lds[buf][1][g][0]);
            size_t boff = (size_t)(cb + g * 16 + l15) * K + (k0 + 8 * l4);
            gload16(Bhi + boff, &lds[buf][2][g][0]);
            if constexpr (TERMS == 3) gload16(Blo + boff, &lds[buf][3][g][0]);
        }
    };

    const int wave_r = (wave >> 1) * 64;
    const int wave_c = (wave & 1) * 64;
    const int ag0 = wave_r >> 4;
    const int bg0 = wave_c >> 4;

    f32x4 acc[4][4] = {};
    const int nks = K >> 5;
    stage(0, 0);
    int buf = 0;
    for (int ks = 0; ks < nks; ks++) {
        __syncthreads();
        if (ks + 1 < nks) stage(buf ^ 1, ks + 1);
        f16x8 ah[4], bh[4], al[4], bl[4];
        #pragma unroll
        for (int i = 0; i < 4; i++) {
            ah[i] = *(const f16x8*)&lds[buf][0][ag0 + i][lane * 8];
            bh[i] = *(const f16x8*)&lds[buf][2][bg0 + i][lane * 8];
            if constexpr (TERMS == 3) {
                al[i] = *(const f16x8*)&lds[buf][1][ag0 + i][lane * 8];
                bl[i] = *(const f16x8*)&lds[buf][3][bg0 + i][lane * 8];
            }
        }
        #pragma unroll
        for (int m = 0; m < 4; m++)
            #pragma unroll
            for (int n = 0; n < 4; n++) {
                acc[m][n] = __builtin_amdgcn_mfma_f32_16x16x32_f16(ah[m], bh[n], acc[m][n], 0, 0, 0);
                if constexpr (TERMS == 3) {
                    acc[m][n] = __builtin_amdgcn_mfma_f32_16x16x32_f16(ah[m], bl[n], acc[m][n], 0, 0, 0);
                    acc[m][n] = __builtin_amdgcn_mfma_f32_16x16x32_f16(al[m], bh[n], acc[m][n], 0, 0, 0);
                }
            }
        buf ^= 1;
    }
    #pragma unroll
    for (int m = 0; m < 4; m++)
        #pragma unroll
        for (int n = 0; n < 4; n++) {
            int r0 = rb + wave_r + m * 16 + l4 * 4;
            int c  = cb + wave_c + n * 16 + l15;
            #pragma unroll
            for (int reg = 0; reg < 4; reg++)
                C[(size_t)(r0 + reg) * ldc + c] = acc[m][n][reg];
        }
}

// ---------------- attention scores + softmax + mem_read (one block per n) ----------------
__global__ __launch_bounds__(256)
void attn_memread(const __half* __restrict__ mv, const float* __restrict__ wq,
                  const float* __restrict__ gmask, __half* __restrict__ mem_read)
{
    int n = blockIdx.x;
    __shared__ __align__(16) __half smv[TT][1032];
    __shared__ float sw[HH][TT];
    __shared__ float ssm[HH][TT];
    int tid = threadIdx.x;

    for (int t = 0; t < TT; t++) {
        const ushort4* src = (const ushort4*)(mv + ((size_t)t * NN + n) * MM);
        ((ushort4*)&smv[t][0])[tid] = src[tid];
    }
    __syncthreads();

    // scores: all 256 threads; tid -> (h, t, half), combine halves via shfl
    {
        int h    = tid >> 5;          // 0..7
        int t    = (tid >> 1) & 15;   // 0..15
        int half = tid & 1;
        const float* w = wq + h * MM;
        float acc = 0.f;
        int m0 = half * 512;
        for (int m = m0; m < m0 + 512; m += 2) {
            float2 v = __half22float2(*(const __half2*)&smv[t][m]);
            acc = fmaf(v.x, w[m], acc);
            acc = fmaf(v.y, w[m + 1], acc);
        }
        acc += __shfl_xor(acc, 1, 64);
        if (half == 0) sw[h][t] = acc;
    }
    __syncthreads();
    if (tid < 8) {
        int h = tid;
        float mx = -1e30f;
        for (int t = 0; t < TT; t++) mx = fmaxf(mx, sw[h][t]);
        float s = 0.f;
        for (int t = 0; t < TT; t++) { float e = __expf(sw[h][t] - mx); ssm[h][t] = e; s += e; }
        float inv = 1.0f / s;
        for (int t = 0; t < TT; t++) ssm[h][t] *= inv;
    }
    __syncthreads();

    const float* gm = gmask + (size_t)n * MM;
    #pragma unroll
    for (int mm = 0; mm < 4; mm++) {
        int m = tid + mm * 256;
        int h = m >> 7;
        float acc = 0.f;
        #pragma unroll
        for (int t = 0; t < TT; t++) acc = fmaf(__half2float(smv[t][m]), ssm[h][t], acc);
        acc *= gm[m];
        mem_read[(size_t)n * MM + m] = __float2half(acc);
    }
}

// ---------------- LayerNorm + residual broadcast over T (one block per n) ----------------
__global__ __launch_bounds__(256)
void ln_add(const float* __restrict__ mem_out, const float* __restrict__ x,
            const float* __restrict__ gamma, const float* __restrict__ beta,
            const float* __restrict__ mmix, float* __restrict__ out)
{
    int n = blockIdx.x, tid = threadIdx.x;
    int lane = tid & 63, wave = tid >> 6;
    __shared__ float sred[10];
    float4 v = ((const float4*)(mem_out + (size_t)n * DD))[tid];
    float s  = v.x + v.y + v.z + v.w;
    float ss = v.x * v.x + v.y * v.y + v.z * v.z + v.w * v.w;
    #pragma unroll
    for (int o = 32; o > 0; o >>= 1) { s += __shfl_down(s, o, 64); ss += __shfl_down(ss, o, 64); }
    if (lane == 0) { sred[wave * 2] = s; sred[wave * 2 + 1] = ss; }
    __syncthreads();
    if (tid == 0) {
        float S = 0.f, SS = 0.f;
        for (int w = 0; w < 4; w++) { S += sred[w * 2]; SS += sred[w * 2 + 1]; }
        float mu = S * (1.0f / DD);
        float var = SS * (1.0f / DD) - mu * mu;
        sred[8] = mu;
        sred[9] = rsqrtf(var + 1e-5f);
    }
    __syncthreads();
    float mu = sred[8], rs = sred[9];
    float4 g = ((const float4*)gamma)[tid];
    float4 b = ((const float4*)beta)[tid];
    float4 nv;
    nv.x = (v.x - mu) * rs * g.x + b.x;
    nv.y = (v.y - mu) * rs * g.y + b.y;
    nv.z = (v.z - mu) * rs * g.z + b.z;
    nv.w = (v.w - mu) * rs * g.w + b.w;
    float mix = 1.0f / (1.0f + expf(-mmix[0]));
    for (int t = 0; t < TT; t++) {
        size_t off = ((size_t)t * NN + n) * DD;
        float4 xv = ((const float4*)(x + off))[tid];
        float4 o;
        o.x = xv.x + mix * nv.x;
        o.y = xv.y + mix * nv.y;
        o.z = xv.z + mix * nv.z;
        o.w = xv.w + mix * nv.w;
        ((float4*)(out + off))[tid] = o;
    }
}

__global__ void ws_sentinel(float* out) { out[0] = 12345.0f; }

extern "C" void kernel_launch(void* const* d_in, const int* in_sizes, int n_in,
                              void* d_out, int out_size, void* d_ws, size_t ws_size,
                              hipStream_t stream)
{
    const float* x     = (const float*)d_in[0];
    const float* Wto   = (const float*)d_in[1];
    const float* Wg    = (const float*)d_in[2];
    const float* Wrk   = (const float*)d_in[3];
    const float* Wfrom = (const float*)d_in[4];
    const float* q     = (const float*)d_in[5];
    const float* gthr  = (const float*)d_in[6];
    const float* gamma = (const float*)d_in[7];
    const float* beta  = (const float*)d_in[8];
    const float* mmix  = (const float*)d_in[9];
    float* out = (float*)d_out;

    char* w = (char*)d_ws;
    size_t off = 0;
    auto alloc = [&](size_t bytes) -> void* {
        void* p = w + off;
        off += (bytes + 255) & ~(size_t)255;
        return p;
    };
    __half* x_hi   = (__half*)alloc((size_t)ROWS * DD * 2);     // 64 MB (tiled+perm)
    __half* x_lo   = (__half*)alloc((size_t)ROWS * DD * 2);     // 64 MB (tiled+perm)
    __half* wc_hi  = (__half*)alloc((size_t)JJ * DD * 2);       // 4 MB (tiled)
    __half* wc_lo  = (__half*)alloc((size_t)JJ * DD * 2);       // 4 MB (tiled)
    __half* wf_hi  = (__half*)alloc((size_t)DD * MM * 2);       // 2 MB (row-major)
    float*  wq     = (float*) alloc((size_t)HH * MM * 4);
    __half* mv     = (__half*)alloc((size_t)TT * NN * MM * 2);  // 64 MB
    float*  gmask  = (float*) alloc((size_t)NN * MM * 4);       // 8 MB
    __half* m_read = (__half*)alloc((size_t)NN * MM * 2);       // 4 MB
    float*  m_out  = (float*) alloc((size_t)NN * DD * 4);       // 8 MB

    if (off > ws_size) {
        ws_sentinel<<<1, 1, 0, stream>>>(out);
        return;
    }

    // allow 128 KiB dynamic LDS for gemm8p (deterministic, capture-safe)
    hipFuncSetAttribute((const void*)gemm8p, hipFuncAttributeMaxDynamicSharedMemorySize, 131072);

    // 1) packs (tiled K-major for GEMM operands)
    pack_tiled<true><<<(ROWS / 256) * 16, 256, 0, stream>>>(x, x_hi, x_lo);
    pack_tiled_w<<<128, 256, 0, stream>>>(Wto, Wg, wc_hi, wc_lo);
    pack_hi<<<(DD * MM / 4 + 255) / 256, 256, 0, stream>>>(Wfrom, wf_hi, DD * MM / 4);
    compute_wq<<<dim3(4, 8), 256, 0, stream>>>(Wrk, q, wq);

    // 2) big 3-term f16 GEMM (16x16x32 MFMA, tiled K-major, R15 schedule) + fused LIF
    gemm8p<<<(ROWS / 256) * (JJ / 256), 512, 131072, stream>>>(x_hi, x_lo, wc_hi, wc_lo, mv, gmask, gthr);

    // 3) attention scores + softmax + gated mem_read
    attn_memread<<<NN, 256, 0, stream>>>(mv, wq, gmask, m_read);

    // 4) mem_out = mem_read @ W_from^T  (2048 x 1024, K=1024), single-term f16
    gemm_f16<1><<<(NN / 128) * (DD / 128), 256, 0, stream>>>(m_read, m_read, wf_hi, wf_hi, m_out, MM, DD, 3);

    // 5) LayerNorm + residual broadcast over T
    ln_add<<<NN, 256, 0, stream>>>(m_out, x, gamma, beta, mmix, out);
}

// Round 18
// 486.110 us; speedup vs baseline: 1.0398x; 1.0398x over previous
//
#include <hip/hip_runtime.h>
#include <hip/hip_bf16.h>
#include <hip/hip_fp16.h>

// Problem constants
#define TT 16
#define NN 2048          // B*S
#define DD 1024
#define MM 1024
#define HH 8
#define ROWS 32768       // T*N
#define JJ 2048          // 2*M (mi | gi packed)

typedef _Float16 f16x8 __attribute__((ext_vector_type(8)));
typedef float f32x4 __attribute__((ext_vector_type(4)));
typedef unsigned short u16x8 __attribute__((ext_vector_type(8)));

#define SB  __builtin_amdgcn_sched_barrier(0)
#define BAR __builtin_amdgcn_s_barrier()

__device__ __forceinline__ void gload16(const void* g, void* l) {
    __builtin_amdgcn_global_load_lds((const __attribute__((address_space(1))) void*)g,
                                     (__attribute__((address_space(3))) void*)l, 16, 0, 0);
}

// ---------------- pack fp32 -> f16 hi only (row-major, for W_from) ----------------
__global__ __launch_bounds__(256) void pack_hi(const float* __restrict__ in,
                                               __half* __restrict__ hi, long n4) {
    long i = (long)blockIdx.x * 256 + threadIdx.x;
    if (i >= n4) return;
    float4 v = ((const float4*)in)[i];
    ushort4 H = { __half_as_ushort(__float2half(v.x)), __half_as_ushort(__float2half(v.y)),
                  __half_as_ushort(__float2half(v.z)), __half_as_ushort(__float2half(v.w)) };
    ((ushort4*)hi)[i] = H;
}

// ---------------- pack fp32 -> f16 hi/lo into TILED K-major global layout ----
// Output: per 256-row block rblk, per BK=32 k-tile kt: 16KB tile
//   [slot 0..3][row 0..255][16B(8 halfs)], tiles ordered (rblk*32 + kt).
// Tile (rblk,kt) slot s row r holds halfs of floats in[src_row][kt*32+s*8 .. +8]
// (slot = k-slot l4 of the 16x16x32 fragment).
// PERM=true applies the 16x16 LIF row permutation (R8):
//   r bits [n3 n2 t3 t2 n1 n0 t1 t0]:
//   t = ((r>>4)&3)*4 + (r&3), n_l = ((r>>7)&1)*8+((r>>6)&1)*4+((r>>2)&3)
// One block = (rblk, kt2), kt2 covers kt = 2*kt2, 2*kt2+1 (64 floats of k).
template<bool PERM>
__global__ __launch_bounds__(256)
void pack_tiled(const float* __restrict__ in, __half* __restrict__ hi,
                __half* __restrict__ lo) {
    const int rblk = blockIdx.x >> 4;
    const int kt2  = blockIdx.x & 15;
    const int r    = threadIdx.x;
    int src_row;
    if (PERM) {
        int t   = ((r >> 4) & 3) * 4 + (r & 3);
        int n_l = ((r >> 7) & 1) * 8 + ((r >> 6) & 1) * 4 + ((r >> 2) & 3);
        src_row = t * NN + rblk * 16 + n_l;
    } else {
        src_row = rblk * 256 + r;
    }
    const float4* s4 = (const float4*)(in + (size_t)src_row * 1024 + kt2 * 64);
    float f[64];
    #pragma unroll
    for (int q = 0; q < 16; q++) {
        float4 v = s4[q];
        f[q * 4 + 0] = v.x; f[q * 4 + 1] = v.y; f[q * 4 + 2] = v.z; f[q * 4 + 3] = v.w;
    }
    #pragma unroll
    for (int j = 0; j < 8; j++) {           // j -> (kt_local = j>>2, slot = j&3)
        u16x8 H, L;
        #pragma unroll
        for (int e = 0; e < 8; e++) {
            float x = f[j * 8 + e];
            __half h = __float2half(x);
            H[e] = __half_as_ushort(h);
            L[e] = __half_as_ushort(__float2half(x - __half2float(h)));
        }
        size_t off = ((size_t)(rblk * 32 + kt2 * 2 + (j >> 2))) * 8192 + (j & 3) * 2048 + r * 8;
        *(u16x8*)(hi + off) = H;
        *(u16x8*)(lo + off) = L;
    }
}

// ---- merged W pack + wq: blocks [0,64) Wto, [64,128) Wg (tiled), [128,160) wq ----
__global__ __launch_bounds__(256)
void pack_tiled_w(const float* __restrict__ Wto, const float* __restrict__ Wg,
                  __half* __restrict__ hi, __half* __restrict__ lo,
                  const float* __restrict__ Wrk, const float* __restrict__ q,
                  float* __restrict__ wq) {
    if (blockIdx.x >= 128) {
        // compute_wq: wq[h][m] = scale * sum_hd q[h,hd]*Wrk[h*128+hd, m]
        int bid = blockIdx.x - 128;          // 0..31
        int m = (bid & 3) * 256 + threadIdx.x;
        int h = bid >> 2;                    // 0..7
        const float* qh = q + h * 128;
        const float* wr = Wrk + (size_t)h * 128 * MM + m;
        float acc = 0.f;
        for (int hd = 0; hd < 128; hd++) acc = fmaf(qh[hd], wr[(size_t)hd * MM], acc);
        wq[h * MM + m] = acc * 0.08838834764831845f;   // 1/sqrt(128)
        return;
    }
    const int half = blockIdx.x >> 6;         // 0: Wto, 1: Wg
    const int bid  = blockIdx.x & 63;
    const int rblk = bid >> 4;
    const int kt2  = bid & 15;
    const int r    = threadIdx.x;
    const float* in = half ? Wg : Wto;
    __half* hio = hi + (size_t)half * MM * DD;
    __half* loo = lo + (size_t)half * MM * DD;
    const int src_row = rblk * 256 + r;
    const float4* s4 = (const float4*)(in + (size_t)src_row * 1024 + kt2 * 64);
    float f[64];
    #pragma unroll
    for (int qq = 0; qq < 16; qq++) {
        float4 v = s4[qq];
        f[qq * 4 + 0] = v.x; f[qq * 4 + 1] = v.y; f[qq * 4 + 2] = v.z; f[qq * 4 + 3] = v.w;
    }
    #pragma unroll
    for (int j = 0; j < 8; j++) {
        u16x8 H, L;
        #pragma unroll
        for (int e = 0; e < 8; e++) {
            float x = f[j * 8 + e];
            __half h = __float2half(x);
            H[e] = __half_as_ushort(h);
            L[e] = __half_as_ushort(__float2half(x - __half2float(h)));
        }
        size_t off = ((size_t)(rblk * 32 + kt2 * 2 + (j >> 2))) * 8192 + (j & 3) * 2048 + r * 8;
        *(u16x8*)(hio + off) = H;
        *(u16x8*)(loo + off) = L;
    }
}

// =============================================================================
// 256x256 3-term f16 GEMM, 16x16x32 MFMA (triplet {Ahi*Bh, Ahi*Bl, Alo*Bh},
// barrier-slim) + FUSED LIF EPILOGUE. Tiled K-major global layout.
// R15 structure (best measured: 296.7 us, MfmaUtil 65%): phased triplet,
// one vmcnt(0)+s_barrier per triplet; staging = pure linear 16KB copy;
// fragment read = slot(l4)*4096 + row*16 (conflict-free, no swizzle VALU).
// =============================================================================
__global__ __launch_bounds__(512, 2)
void gemm8p(const __half* __restrict__ Ahi, const __half* __restrict__ Alo,
            const __half* __restrict__ Bhi, const __half* __restrict__ Blo,
            __half* __restrict__ mv, float* __restrict__ gmask,
            const float* __restrict__ gate_thr)
{
    extern __shared__ __align__(16) char smem[];
    char* AHb = smem;                 // [2 parity][16384 B] each
    char* ALb = smem + 32768;
    char* BHb = smem + 65536;
    char* BLb = smem + 98304;

    const int tid = threadIdx.x, lane = tid & 63, wave = tid >> 6;
    const int l15 = lane & 15, l4 = lane >> 4;
    const int wm = wave >> 2, wn = wave & 3;

    // XCD-contiguous swizzle (1024 blocks), col-fastest within chunk.
    const int orig = blockIdx.x;
    const int wg   = (orig & 7) * 128 + (orig >> 3);
    const int rb   = (wg >> 3) * 256;
    const int cb   = (wg & 7) * 256;

    // Stage 8KB slice s of a 16KB K-major tile: pure linear copy.
    auto stageU = [&](const __half* src, int row0, char* dstbase, int par, int kt, int s) {
        const char* g = (const char*)(src + (size_t)((row0 >> 8) * 32 + kt) * 8192)
                        + (size_t)(s * 512 + tid) * 16;
        gload16(g, dstbase + par * 16384 + (size_t)(s * 512 + wave * 64) * 16);
    };
    // 16x16 fragment read: lane -> slot l4, row = caller's rowblk + l15.
    auto rdT = [&](const char* base, int par, int row) -> f16x8 {
        return *(const f16x8*)(base + par * 16384 + l4 * 4096 + row * 16);
    };

    f32x4 acc[8][4] = {};
    const int NKT = 32;                     // k0 triplets

    // Prologue: stage triplet 0 (parity 0), 8 loads/thread.
    stageU(Ahi, rb, AHb, 0, 0, 0); stageU(Ahi, rb, AHb, 0, 0, 1);
    stageU(Alo, rb, ALb, 0, 0, 0); stageU(Alo, rb, ALb, 0, 0, 1);
    stageU(Bhi, cb, BHb, 0, 0, 0); stageU(Bhi, cb, BHb, 0, 0, 1);
    stageU(Blo, cb, BLb, 0, 0, 0); stageU(Blo, cb, BLb, 0, 0, 1);

    for (int kt = 0; kt < NKT; kt++) {
        const int p = kt & 1, pn = p ^ 1;
        const bool pre = (kt + 1 < NKT);
        f16x8 a[8], bh[4], bl[4];

        // ---- triplet-start sync: parity-p tiles all present across waves
        asm volatile("s_waitcnt vmcnt(0)" ::: "memory");
        SB; BAR;

        #pragma unroll
        for (int i = 0; i < 8; i++) a[i] = rdT(AHb, p, wm * 128 + i * 16 + l15);
        #pragma unroll
        for (int n = 0; n < 4; n++) bh[n] = rdT(BHb, p, wn * 64 + n * 16 + l15);
        if (pre) {
            stageU(Ahi, rb, AHb, pn, kt + 1, 0); stageU(Ahi, rb, AHb, pn, kt + 1, 1);
            stageU(Alo, rb, ALb, pn, kt + 1, 0); stageU(Alo, rb, ALb, pn, kt + 1, 1);
        }
        __builtin_amdgcn_s_setprio(1);
        #pragma unroll
        for (int i = 0; i < 8; i++)
            #pragma unroll
            for (int n = 0; n < 4; n++)
                acc[i][n] = __builtin_amdgcn_mfma_f32_16x16x32_f16(a[i], bh[n], acc[i][n], 0, 0, 0);
        __builtin_amdgcn_s_setprio(0);

        #pragma unroll
        for (int n = 0; n < 4; n++) bl[n] = rdT(BLb, p, wn * 64 + n * 16 + l15);
        if (pre) {
            stageU(Bhi, cb, BHb, pn, kt + 1, 0); stageU(Bhi, cb, BHb, pn, kt + 1, 1);
        }
        __builtin_amdgcn_s_setprio(1);
        #pragma unroll
        for (int i = 0; i < 8; i++)
            #pragma unroll
            for (int n = 0; n < 4; n++)
                acc[i][n] = __builtin_amdgcn_mfma_f32_16x16x32_f16(a[i], bl[n], acc[i][n], 0, 0, 0);
        __builtin_amdgcn_s_setprio(0);

        #pragma unroll
        for (int i = 0; i < 8; i++) a[i] = rdT(ALb, p, wm * 128 + i * 16 + l15);
        if (pre) {
            stageU(Blo, cb, BLb, pn, kt + 1, 0); stageU(Blo, cb, BLb, pn, kt + 1, 1);
        }
        __builtin_amdgcn_s_setprio(1);
        #pragma unroll
        for (int i = 0; i < 8; i++)
            #pragma unroll
            for (int n = 0; n < 4; n++)
                acc[i][n] = __builtin_amdgcn_mfma_f32_16x16x32_f16(a[i], bh[n], acc[i][n], 0, 0, 0);
        __builtin_amdgcn_s_setprio(0);
    }

    // ===== fused LIF epilogue =====
    asm volatile("s_waitcnt lgkmcnt(0) vmcnt(0)" ::: "memory");
    SB; BAR;

    const int n_g_base = rb >> 4;       // 16 n per block
    if (cb < 1024) {
        // memory path: tau=0.99, pre-reset trace -> LDS [16t][16n][256m] f16 -> mv
        __half* mvs = (__half*)smem;
        #pragma unroll
        for (int i2 = 0; i2 < 2; i2++) {
            int n_l = wm * 8 + i2 * 4 + l4;
            #pragma unroll
            for (int nf = 0; nf < 4; nf++) {
                int col = wn * 64 + nf * 16 + l15;
                float v = 0.f;
                #pragma unroll
                for (int tt = 0; tt < 4; tt++)
                    #pragma unroll
                    for (int reg = 0; reg < 4; reg++) {
                        int t = tt * 4 + reg;
                        v = 0.99f * v + acc[i2 * 4 + tt][nf][reg];
                        mvs[(t * 16 + n_l) * 256 + col] = __float2half(v);
                        if (v >= 1.0f) v -= 1.0f;
                    }
            }
        }
        SB; BAR;
        // cooperative vector store: 8192 x 16B chunks
        #pragma unroll
        for (int j = 0; j < 16; j++) {
            int k = j * 512 + tid;
            int e = k * 8;
            int t   = e >> 12;
            int n_l = (e >> 8) & 15;
            int m   = e & 255;
            float4 val = *(const float4*)((const char*)smem + (size_t)k * 16);
            *(float4*)(mv + ((size_t)(t * NN + n_g_base + n_l) * MM + cb + m)) = val;
        }
    } else {
        // gate path: tau=0.9, spike count -> gmask
        float thr = gate_thr[0];
        #pragma unroll
        for (int i2 = 0; i2 < 2; i2++) {
            int n_l = wm * 8 + i2 * 4 + l4;
            #pragma unroll
            for (int nf = 0; nf < 4; nf++) {
                int col = wn * 64 + nf * 16 + l15;
                float v = 0.f, cnt = 0.f;
                #pragma unroll
                for (int tt = 0; tt < 4; tt++)
                    #pragma unroll
                    for (int reg = 0; reg < 4; reg++) {
                        v = 0.9f * v + acc[i2 * 4 + tt][nf][reg];
                        if (v >= 1.0f) { v -= 1.0f; cnt += 1.0f; }
                    }
                float gs = cnt * 0.0625f;
                gmask[(size_t)(n_g_base + n_l) * MM + (cb - 1024) + col] =
                    1.0f / (1.0f + expf(-10.0f * (gs - thr)));
            }
        }
    }
}

// ---------------- 128x128 f16 GEMM (kept for the small projection) ----------------
template<int TERMS>
__global__ __launch_bounds__(256, 2)
void gemm_f16(const __half* __restrict__ Ahi, const __half* __restrict__ Alo,
              const __half* __restrict__ Bhi, const __half* __restrict__ Blo,
              float* __restrict__ C, int K, int ldc, int ncb_log2)
{
    __shared__ __align__(16) __half lds[2][4][8][512];
    const int tid  = threadIdx.x;
    const int lane = tid & 63;
    const int wave = tid >> 6;
    const int l15  = lane & 15, l4 = lane >> 4;

    const int nwg  = gridDim.x;
    const int orig = blockIdx.x;
    const int wg   = (orig & 7) * (nwg >> 3) + (orig >> 3);
    const int rb = (wg >> ncb_log2) * 128;
    const int cb = (wg & ((1 << ncb_log2) - 1)) * 128;

    auto stage = [&](int buf, int ks) {
        const int k0 = ks * 32;
        #pragma unroll
        for (int qq = 0; qq < 2; qq++) {
            int g = wave * 2 + qq;
            size_t aoff = (size_t)(rb + g * 16 + l15) * K + (k0 + 8 * l4);
            gload16(Ahi + aoff, &lds[buf][0][g][0]);
            if constexpr (TERMS == 3) gload16(Alo + aoff, &lds[buf][1][g][0]);
            size_t boff = (size_t)(cb + g * 16 + l15) * K + (k0 + 8 * l4);
            gload16(Bhi + boff, &lds[buf][2][g][0]);
            if constexpr (TERMS == 3) gload16(Blo + boff, &lds[buf][3][g][0]);
        }
    };

    const int wave_r = (wave >> 1) * 64;
    const int wave_c = (wave & 1) * 64;
    const int ag0 = wave_r >> 4;
    const int bg0 = wave_c >> 4;

    f32x4 acc[4][4] = {};
    const int nks = K >> 5;
    stage(0, 0);
    int buf = 0;
    for (int ks = 0; ks < nks; ks++) {
        __syncthreads();
        if (ks + 1 < nks) stage(buf ^ 1, ks + 1);
        f16x8 ah[4], bh[4], al[4], bl[4];
        #pragma unroll
        for (int i = 0; i < 4; i++) {
            ah[i] = *(const f16x8*)&lds[buf][0][ag0 + i][lane * 8];
            bh[i] = *(const f16x8*)&lds[buf][2][bg0 + i][lane * 8];
            if constexpr (TERMS == 3) {
                al[i] = *(const f16x8*)&lds[buf][1][ag0 + i][lane * 8];
                bl[i] = *(const f16x8*)&lds[buf][3][bg0 + i][lane * 8];
            }
        }
        #pragma unroll
        for (int m = 0; m < 4; m++)
            #pragma unroll
            for (int n = 0; n < 4; n++) {
                acc[m][n] = __builtin_amdgcn_mfma_f32_16x16x32_f16(ah[m], bh[n], acc[m][n], 0, 0, 0);
                if constexpr (TERMS == 3) {
                    acc[m][n] = __builtin_amdgcn_mfma_f32_16x16x32_f16(ah[m], bl[n], acc[m][n], 0, 0, 0);
                    acc[m][n] = __builtin_amdgcn_mfma_f32_16x16x32_f16(al[m], bh[n], acc[m][n], 0, 0, 0);
                }
            }
        buf ^= 1;
    }
    #pragma unroll
    for (int m = 0; m < 4; m++)
        #pragma unroll
        for (int n = 0; n < 4; n++) {
            int r0 = rb + wave_r + m * 16 + l4 * 4;
            int c  = cb + wave_c + n * 16 + l15;
            #pragma unroll
            for (int reg = 0; reg < 4; reg++)
                C[(size_t)(r0 + reg) * ldc + c] = acc[m][n][reg];
        }
}

// ---------------- attention scores + softmax + mem_read (one block per n) ----------------
__global__ __launch_bounds__(256)
void attn_memread(const __half* __restrict__ mv, const float* __restrict__ wq,
                  const float* __restrict__ gmask, __half* __restrict__ mem_read)
{
    int n = blockIdx.x;
    __shared__ __align__(16) __half smv[TT][1032];
    __shared__ float sw[HH][TT];
    __shared__ float ssm[HH][TT];
    int tid = threadIdx.x;

    for (int t = 0; t < TT; t++) {
        const ushort4* src = (const ushort4*)(mv + ((size_t)t * NN + n) * MM);
        ((ushort4*)&smv[t][0])[tid] = src[tid];
    }
    __syncthreads();

    if (tid < 128) {
        int h = tid >> 4, t = tid & 15;
        const float* w = wq + h * MM;
        float acc = 0.f;
        for (int m = 0; m < MM; m += 2) {
            float2 v = __half22float2(*(const __half2*)&smv[t][m]);
            acc = fmaf(v.x, w[m], acc);
            acc = fmaf(v.y, w[m + 1], acc);
        }
        sw[h][t] = acc;
    }
    __syncthreads();
    if (tid < 8) {
        int h = tid;
        float mx = -1e30f;
        for (int t = 0; t < TT; t++) mx = fmaxf(mx, sw[h][t]);
        float s = 0.f;
        for (int t = 0; t < TT; t++) { float e = __expf(sw[h][t] - mx); ssm[h][t] = e; s += e; }
        float inv = 1.0f / s;
        for (int t = 0; t < TT; t++) ssm[h][t] *= inv;
    }
    __syncthreads();

    const float* gm = gmask + (size_t)n * MM;
    #pragma unroll
    for (int mm = 0; mm < 4; mm++) {
        int m = tid + mm * 256;
        int h = m >> 7;
        float acc = 0.f;
        #pragma unroll
        for (int t = 0; t < TT; t++) acc = fmaf(__half2float(smv[t][m]), ssm[h][t], acc);
        acc *= gm[m];
        mem_read[(size_t)n * MM + m] = __float2half(acc);
    }
}

// ---------------- LayerNorm + residual broadcast over T (one block per n) ----------------
__global__ __launch_bounds__(256)
void ln_add(const float* __restrict__ mem_out, const float* __restrict__ x,
            const float* __restrict__ gamma, const float* __restrict__ beta,
            const float* __restrict__ mmix, float* __restrict__ out)
{
    int n = blockIdx.x, tid = threadIdx.x;
    int lane = tid & 63, wave = tid >> 6;
    __shared__ float sred[10];
    float4 v = ((const float4*)(mem_out + (size_t)n * DD))[tid];
    float s  = v.x + v.y + v.z + v.w;
    float ss = v.x * v.x + v.y * v.y + v.z * v.z + v.w * v.w;
    #pragma unroll
    for (int o = 32; o > 0; o >>= 1) { s += __shfl_down(s, o, 64); ss += __shfl_down(ss, o, 64); }
    if (lane == 0) { sred[wave * 2] = s; sred[wave * 2 + 1] = ss; }
    __syncthreads();
    if (tid == 0) {
        float S = 0.f, SS = 0.f;
        for (int w = 0; w < 4; w++) { S += sred[w * 2]; SS += sred[w * 2 + 1]; }
        float mu = S * (1.0f / DD);
        float var = SS * (1.0f / DD) - mu * mu;
        sred[8] = mu;
        sred[9] = rsqrtf(var + 1e-5f);
    }
    __syncthreads();
    float mu = sred[8], rs = sred[9];
    float4 g = ((const float4*)gamma)[tid];
    float4 b = ((const float4*)beta)[tid];
    float4 nv;
    nv.x = (v.x - mu) * rs * g.x + b.x;
    nv.y = (v.y - mu) * rs * g.y + b.y;
    nv.z = (v.z - mu) * rs * g.z + b.z;
    nv.w = (v.w - mu) * rs * g.w + b.w;
    float mix = 1.0f / (1.0f + expf(-mmix[0]));
    for (int t = 0; t < TT; t++) {
        size_t off = ((size_t)t * NN + n) * DD;
        float4 xv = ((const float4*)(x + off))[tid];
        float4 o;
        o.x = xv.x + mix * nv.x;
        o.y = xv.y + mix * nv.y;
        o.z = xv.z + mix * nv.z;
        o.w = xv.w + mix * nv.w;
        ((float4*)(out + off))[tid] = o;
    }
}

__global__ void ws_sentinel(float* out) { out[0] = 12345.0f; }

extern "C" void kernel_launch(void* const* d_in, const int* in_sizes, int n_in,
                              void* d_out, int out_size, void* d_ws, size_t ws_size,
                              hipStream_t stream)
{
    const float* x     = (const float*)d_in[0];
    const float* Wto   = (const float*)d_in[1];
    const float* Wg    = (const float*)d_in[2];
    const float* Wrk   = (const float*)d_in[3];
    const float* Wfrom = (const float*)d_in[4];
    const float* q     = (const float*)d_in[5];
    const float* gthr  = (const float*)d_in[6];
    const float* gamma = (const float*)d_in[7];
    const float* beta  = (const float*)d_in[8];
    const float* mmix  = (const float*)d_in[9];
    float* out = (float*)d_out;

    char* w = (char*)d_ws;
    size_t off = 0;
    auto alloc = [&](size_t bytes) -> void* {
        void* p = w + off;
        off += (bytes + 255) & ~(size_t)255;
        return p;
    };
    __half* x_hi   = (__half*)alloc((size_t)ROWS * DD * 2);     // 64 MB (tiled+perm)
    __half* x_lo   = (__half*)alloc((size_t)ROWS * DD * 2);     // 64 MB (tiled+perm)
    __half* wc_hi  = (__half*)alloc((size_t)JJ * DD * 2);       // 4 MB (tiled)
    __half* wc_lo  = (__half*)alloc((size_t)JJ * DD * 2);       // 4 MB (tiled)
    __half* wf_hi  = (__half*)alloc((size_t)DD * MM * 2);       // 2 MB (row-major)
    float*  wq     = (float*) alloc((size_t)HH * MM * 4);
    __half* mv     = (__half*)alloc((size_t)TT * NN * MM * 2);  // 64 MB
    float*  gmask  = (float*) alloc((size_t)NN * MM * 4);       // 8 MB
    __half* m_read = (__half*)alloc((size_t)NN * MM * 2);       // 4 MB
    float*  m_out  = (float*) alloc((size_t)NN * DD * 4);       // 8 MB

    if (off > ws_size) {
        ws_sentinel<<<1, 1, 0, stream>>>(out);
        return;
    }

    // allow 128 KiB dynamic LDS for gemm8p (deterministic, capture-safe)
    hipFuncSetAttribute((const void*)gemm8p, hipFuncAttributeMaxDynamicSharedMemorySize, 131072);

    // 1) packs (tiled K-major for GEMM operands; W-pack + wq merged)
    pack_tiled<true><<<(ROWS / 256) * 16, 256, 0, stream>>>(x, x_hi, x_lo);
    pack_tiled_w<<<160, 256, 0, stream>>>(Wto, Wg, wc_hi, wc_lo, Wrk, q, wq);
    pack_hi<<<(DD * MM / 4 + 255) / 256, 256, 0, stream>>>(Wfrom, wf_hi, DD * MM / 4);

    // 2) big 3-term f16 GEMM (16x16x32 MFMA, tiled K-major, R15 schedule) + fused LIF
    gemm8p<<<(ROWS / 256) * (JJ / 256), 512, 131072, stream>>>(x_hi, x_lo, wc_hi, wc_lo, mv, gmask, gthr);

    // 3) attention scores + softmax + gated mem_read (R15 form)
    attn_memread<<<NN, 256, 0, stream>>>(mv, wq, gmask, m_read);

    // 4) mem_out = mem_read @ W_from^T  (2048 x 1024, K=1024), single-term f16
    gemm_f16<1><<<(NN / 128) * (DD / 128), 256, 0, stream>>>(m_read, m_read, wf_hi, wf_hi, m_out, MM, DD, 3);

    // 5) LayerNorm + residual broadcast over T
    ln_add<<<NN, 256, 0, stream>>>(m_out, x, gamma, beta, mmix, out);
}